// Round 13
// baseline (431.699 us; speedup 1.0000x reference)
//
#include <hip/hip_runtime.h>

#define NN 10000
#define NEDGE 160000
#define NBATCH 64
#define TABN 4096

// ---------------- workspace layout (units: floats) ----------------
static constexpr size_t OFF_POS   = 0;                     // N*3
static constexpr size_t OFF_H     = 30016;                 // N*64
static constexpr size_t OFF_NF0   = OFF_H   + 640000;      // N*64
static constexpr size_t OFF_NUP   = OFF_NF0 + 640000;      // N*64
static constexpr size_t OFF_V3    = OFF_NUP + 640000;      // N*192
static constexpr size_t OFF_TAB   = OFF_V3  + 1920000;     // 4096*64 r-table
static constexpr size_t OFF_AGG   = OFF_TAB + 640000;      // N*256 (float4[N*64])
static constexpr size_t OFF_WW    = OFF_AGG + 2560000;     // E*64
static constexpr size_t OFF_WY    = OFF_WW  + 10240000;    // E*4 (float4[E])
static constexpr size_t OFF_ESLOT = OFF_WY  + 640000;      // E ints
static constexpr size_t OFF_CSR   = OFF_ESLOT + 160000;    // N+1 ints (pad 10016)
static constexpr size_t OFF_CNT   = OFF_CSR + 10016;       // N ints
static constexpr size_t OFF_CUR   = OFF_CNT + 10016;       // N ints
static constexpr size_t OFF_BACC  = OFF_CUR + 10016;       // B*4 floats
static constexpr size_t OFF_MAXL  = OFF_BACC + 256;        // 1 float (pad 16)
static constexpr size_t WS_END    = OFF_MAXL + 16;

__device__ __forceinline__ float silu_f(float x) {
  return x / (1.0f + __expf(-x));
}

// ---------------- setup ----------------
__global__ __launch_bounds__(256) void k_embed_count_up(
    const float* __restrict__ pos_in, const float* __restrict__ na,
    const float* __restrict__ t, const int* __restrict__ batch,
    const float* __restrict__ Wemb, const float* __restrict__ bemb,
    const float* __restrict__ Wup0,
    float* __restrict__ h, float* __restrict__ nf0, float* __restrict__ pos_cur,
    float* __restrict__ nfup0,
    const int* __restrict__ ei, int* __restrict__ counts) {
  if (blockIdx.x >= 2500) {
    int e = (blockIdx.x - 2500) * 256 + threadIdx.x;   // exactly E threads
    atomicAdd(&counts[ei[NEDGE + e]], 1);
    return;
  }
  __shared__ float sx[4][64];
  int tid = blockIdx.x * 256 + threadIdx.x;   // exactly N*64 threads
  int n = tid >> 6, k = tid & 63;
  int w = threadIdx.x >> 6;
  float acc = bemb[k];
  const float* arow = na + n * 10;
#pragma unroll
  for (int j = 0; j < 10; ++j)
    acc = fmaf(arow[j] * 0.25f, Wemb[j * 64 + k], acc);
  acc = fmaf(t[batch[n]], Wemb[10 * 64 + k], acc);
  h[tid] = acc;
  nf0[tid] = acc;
  if (k < 3) pos_cur[n * 3 + k] = pos_in[n * 3 + k];
  sx[w][k] = acc;
  __syncthreads();
  float up = 0.f;
  for (int hh = 0; hh < 64; ++hh)
    up = fmaf(sx[w][hh], Wup0[hh * 64 + k], up);
  nfup0[tid] = up;
}

__global__ __launch_bounds__(1024) void k_scan(const int* __restrict__ counts,
                                               int* __restrict__ offs) {
  __shared__ int part[1024];
  int tid = threadIdx.x;
  int base = tid * 10;
  int local[10];
  int s = 0;
#pragma unroll
  for (int j = 0; j < 10; ++j) {
    int idx = base + j;
    int v = (idx < NN) ? counts[idx] : 0;
    local[j] = s;
    s += v;
  }
  part[tid] = s;
  __syncthreads();
  for (int d = 1; d < 1024; d <<= 1) {
    int v = (tid >= d) ? part[tid - d] : 0;
    __syncthreads();
    part[tid] += v;
    __syncthreads();
  }
  int excl = (tid == 0) ? 0 : part[tid - 1];
#pragma unroll
  for (int j = 0; j < 10; ++j) {
    int idx = base + j;
    if (idx < NN) offs[idx] = excl + local[j];
  }
  if (tid == 1023) offs[NN] = excl + s;
}

__global__ __launch_bounds__(256) void k_scatter(
    const int* __restrict__ ei, const int* __restrict__ offs,
    int* __restrict__ cursor, int* __restrict__ eslot) {
  int e = blockIdx.x * 256 + threadIdx.x;
  int r = ei[NEDGE + e];
  int slot = atomicAdd(&cursor[r], 1);
  eslot[e] = offs[r] + slot;
}

// ---------------- per-layer ----------------
// max edge length of current pos (float-bits atomicMax; lens are >= 0)
__global__ __launch_bounds__(256) void k_maxlen(
    const int* __restrict__ ei, const float* __restrict__ shifts,
    const float* __restrict__ pos, int* __restrict__ maxlen_bits) {
  int e = blockIdx.x * 256 + threadIdx.x;     // exactly E threads
  int s = ei[e], r = ei[NEDGE + e];
  float vx = pos[r * 3 + 0] - pos[s * 3 + 0] + shifts[e * 3 + 0];
  float vy = pos[r * 3 + 1] - pos[s * 3 + 1] + shifts[e * 3 + 1];
  float vz = pos[r * 3 + 2] - pos[s * 3 + 2] + shifts[e * 3 + 2];
  float len = sqrtf(vx * vx + vy * vy + vz * vz);
#pragma unroll
  for (int d = 32; d > 0; d >>= 1)
    len = fmaxf(len, __shfl_xor(len, d));
  if ((threadIdx.x & 63) == 0)
    atomicMax(maxlen_bits, __float_as_int(len));
}

// table[s][k] = (silu(len_s * Wr1 + br1) @ Wr2)[k],  len_s = s * maxlen/4095
__global__ __launch_bounds__(256) void k_table(
    const float* __restrict__ Wr1, const float* __restrict__ br1,
    const float* __restrict__ Wr2, const int* __restrict__ maxlen_bits,
    float* __restrict__ table) {
  __shared__ float sl[4][64];
  float maxlen = __int_as_float(*maxlen_bits);
  float cell = maxlen / (float)(TABN - 1);
  int si = threadIdx.x >> 6, hh = threadIdx.x & 63;
  int samp = blockIdx.x * 4 + si;             // grid 1024 -> 4096 samples
  float lenv = (float)samp * cell;
  sl[si][hh] = silu_f(fmaf(lenv, Wr1[hh], br1[hh]));
  __syncthreads();
  int k = hh;
  float acc = 0.f;
  for (int m = 0; m < 64; ++m)
    acc = fmaf(sl[si][m], Wr2[m * 64 + k], acc);
  table[(size_t)samp * 64 + k] = acc;
}

// k_edge v6: table lerp. 1 edge/thread, E threads. Per edge: 2x64-float table
// rows (L2-hot, 1MB table) lerped -> r; w = r * nfup0[snd]; write to CSR slot.
__global__ __launch_bounds__(256) void k_edge(
    const int* __restrict__ ei, const float* __restrict__ shifts,
    const float* __restrict__ pos, const float* __restrict__ nfup0,
    const int* __restrict__ eslot, const float4* __restrict__ table4,
    const int* __restrict__ maxlen_bits,
    float* __restrict__ w_s, float4* __restrict__ y_s) {
  int e = blockIdx.x * 256 + threadIdx.x;     // exactly E threads
  int s = ei[e], r = ei[NEDGE + e];
  float vx = pos[r * 3 + 0] - pos[s * 3 + 0] + shifts[e * 3 + 0];
  float vy = pos[r * 3 + 1] - pos[s * 3 + 1] + shifts[e * 3 + 1];
  float vz = pos[r * 3 + 2] - pos[s * 3 + 2] + shifts[e * 3 + 2];
  float len = sqrtf(vx * vx + vy * vy + vz * vz);
  float inv = 1.0f / (len + 1e-9f);
  int slot = eslot[e];
  const float c1 = 1.7320508f * 0.0625f;      // sqrt(3)/AVG_NEIGH
  y_s[slot] = make_float4(0.0625f, c1 * vx * inv, c1 * vy * inv, c1 * vz * inv);

  float maxlen = __int_as_float(*maxlen_bits);
  float x = len * ((float)(TABN - 1) / maxlen);
  x = fminf(x, (float)(TABN - 1) - 0.0005f);
  int i0 = (int)x;
  float fr = x - (float)i0;

  const float4* ta = table4 + (size_t)i0 * 16;
  const float4* ub = (const float4*)(nfup0 + (size_t)s * 64);
  float4* wrow = (float4*)(w_s + (size_t)slot * 64);
#pragma unroll
  for (int j = 0; j < 16; ++j) {
    float4 a = ta[j];
    float4 b = ta[16 + j];
    float4 u = ub[j];
    float4 o;
    o.x = fmaf(fr, b.x - a.x, a.x) * u.x;
    o.y = fmaf(fr, b.y - a.y, a.y) * u.y;
    o.z = fmaf(fr, b.z - a.z, a.z) * u.z;
    o.w = fmaf(fr, b.w - a.w, a.w) * u.w;
    wrow[j] = o;
  }
}

// wave-per-node CSR gather (unchanged)
__global__ __launch_bounds__(256) void k_gather(
    const int* __restrict__ offs, const float* __restrict__ w_s,
    const float4* __restrict__ y_s, float4* __restrict__ agg) {
  int gtid = blockIdx.x * 256 + threadIdx.x;
  int n = gtid >> 6;
  int lane = threadIdx.x & 63;
  int beg = offs[n], end = offs[n + 1];
  float a0 = 0.f, a1 = 0.f, a2 = 0.f, a3 = 0.f;
  for (int j = beg; j < end; ++j) {
    float w = w_s[(size_t)j * 64 + lane];
    float4 y = y_s[j];
    a0 = fmaf(w, y.x, a0);
    a1 = fmaf(w, y.y, a1);
    a2 = fmaf(w, y.z, a2);
    a3 = fmaf(w, y.w, a3);
  }
  agg[(size_t)n * 64 + lane] = make_float4(a0, a1, a2, a3);
}

// k_mix_prod v2 (unchanged from round 8)
__global__ __launch_bounds__(256) void k_mix_prod(
    const float4* __restrict__ agg, const float* __restrict__ Wmix,
    const float* __restrict__ Wprod, float* __restrict__ nf0,
    float* __restrict__ v3, const float* __restrict__ Wup_next,
    float* __restrict__ nfup0) {
  __shared__ float sMix[4096];
  __shared__ float sProd[4096];
  __shared__ float sUp[4096];
  __shared__ float4 xa[16][65];        // pitch 65 -> quads hit distinct banks
  for (int i = threadIdx.x; i < 4096; i += 256) { sMix[i] = Wmix[i]; sProd[i] = Wprod[i]; }
  if (Wup_next)
    for (int i = threadIdx.x; i < 4096; i += 256) sUp[i] = Wup_next[i];
  int nb = blockIdx.x * 16;
  for (int i = threadIdx.x; i < 1024; i += 256)
    xa[i >> 6][i & 63] = agg[(size_t)nb * 64 + i];
  __syncthreads();

  int lane = threadIdx.x & 63, w = threadIdx.x >> 6;
  int q = lane >> 4, c16 = lane & 15;
  int nloc = w * 4 + q;                // wave-private rows [4w,4w+4)
  int n = nb + nloc;
  int col0 = c16 * 4;

  float4 a0 = {0,0,0,0}, a1 = {0,0,0,0}, a2 = {0,0,0,0}, a3 = {0,0,0,0};
  for (int hh = 0; hh < 64; ++hh) {
    float4 xv = xa[nloc][hh];
    float4 wm = *(const float4*)&sMix[hh * 64 + col0];
    a0.x = fmaf(xv.x, wm.x, a0.x); a0.y = fmaf(xv.y, wm.x, a0.y);
    a0.z = fmaf(xv.z, wm.x, a0.z); a0.w = fmaf(xv.w, wm.x, a0.w);
    a1.x = fmaf(xv.x, wm.y, a1.x); a1.y = fmaf(xv.y, wm.y, a1.y);
    a1.z = fmaf(xv.z, wm.y, a1.z); a1.w = fmaf(xv.w, wm.y, a1.w);
    a2.x = fmaf(xv.x, wm.z, a2.x); a2.y = fmaf(xv.y, wm.z, a2.y);
    a2.z = fmaf(xv.z, wm.z, a2.z); a2.w = fmaf(xv.w, wm.z, a2.w);
    a3.x = fmaf(xv.x, wm.w, a3.x); a3.y = fmaf(xv.y, wm.w, a3.y);
    a3.z = fmaf(xv.z, wm.w, a3.z); a3.w = fmaf(xv.w, wm.w, a3.w);
  }
  {
    float s0 = a0.x, f0 = 1.0f + s0 + s0 * s0;
    float s1 = a1.x, f1 = 1.0f + s1 + s1 * s1;
    float s2 = a2.x, f2 = 1.0f + s2 + s2 * s2;
    float s3 = a3.x, f3 = 1.0f + s3 + s3 * s3;
    a0.x *= f0; a0.y *= f0; a0.z *= f0; a0.w *= f0;
    a1.x *= f1; a1.y *= f1; a1.z *= f1; a1.w *= f1;
    a2.x *= f2; a2.y *= f2; a2.z *= f2; a2.w *= f2;
    a3.x *= f3; a3.y *= f3; a3.z *= f3; a3.w *= f3;
  }
  xa[nloc][col0 + 0] = a0; xa[nloc][col0 + 1] = a1;
  xa[nloc][col0 + 2] = a2; xa[nloc][col0 + 3] = a3;

  float4 p0 = {0,0,0,0}, p1 = {0,0,0,0}, p2 = {0,0,0,0}, p3 = {0,0,0,0};
  for (int hh = 0; hh < 64; ++hh) {
    float4 xv = xa[nloc][hh];
    float4 wm = *(const float4*)&sProd[hh * 64 + col0];
    p0.x = fmaf(xv.x, wm.x, p0.x); p0.y = fmaf(xv.y, wm.x, p0.y);
    p0.z = fmaf(xv.z, wm.x, p0.z); p0.w = fmaf(xv.w, wm.x, p0.w);
    p1.x = fmaf(xv.x, wm.y, p1.x); p1.y = fmaf(xv.y, wm.y, p1.y);
    p1.z = fmaf(xv.z, wm.y, p1.z); p1.w = fmaf(xv.w, wm.y, p1.w);
    p2.x = fmaf(xv.x, wm.z, p2.x); p2.y = fmaf(xv.y, wm.z, p2.y);
    p2.z = fmaf(xv.z, wm.z, p2.z); p2.w = fmaf(xv.w, wm.z, p2.w);
    p3.x = fmaf(xv.x, wm.w, p3.x); p3.y = fmaf(xv.y, wm.w, p3.y);
    p3.z = fmaf(xv.z, wm.w, p3.z); p3.w = fmaf(xv.w, wm.w, p3.w);
  }
  *(float4*)&nf0[(size_t)n * 64 + col0] = make_float4(p0.x, p1.x, p2.x, p3.x);
  {
    float4* v3p = (float4*)&v3[(size_t)n * 192 + col0 * 3];
    v3p[0] = make_float4(p0.y, p0.z, p0.w, p1.y);
    v3p[1] = make_float4(p1.z, p1.w, p2.y, p2.z);
    v3p[2] = make_float4(p2.w, p3.y, p3.z, p3.w);
  }
  if (Wup_next) {
    xa[nloc][col0 + 0] = p0; xa[nloc][col0 + 1] = p1;
    xa[nloc][col0 + 2] = p2; xa[nloc][col0 + 3] = p3;
    float u0 = 0.f, u1 = 0.f, u2 = 0.f, u3 = 0.f;
    for (int hh = 0; hh < 64; ++hh) {
      float xs = xa[nloc][hh].x;
      float4 wu = *(const float4*)&sUp[hh * 64 + col0];
      u0 = fmaf(xs, wu.x, u0); u1 = fmaf(xs, wu.y, u1);
      u2 = fmaf(xs, wu.z, u2); u3 = fmaf(xs, wu.w, u3);
    }
    *(float4*)&nfup0[(size_t)n * 64 + col0] = make_float4(u0, u1, u2, u3);
  }
}

// k_readout_mlp v2 (unchanged from round 8)
__global__ __launch_bounds__(256) void k_readout_mlp(
    const float* __restrict__ nf0, const float* __restrict__ v3,
    const float* __restrict__ Wro1, const float* __restrict__ bro1,
    const float* __restrict__ Wg, const float* __restrict__ wvv,
    const float* __restrict__ Wro2,
    const float* __restrict__ Wmlp1, const float* __restrict__ bmlp1,
    const float* __restrict__ Wmlp2, const float* __restrict__ bmlp2,
    float* __restrict__ pos, float* __restrict__ h) {
  __shared__ float sR[4096];
  __shared__ float sG[4096];
  __shared__ float sRo2[4096];
  __shared__ float sM1[8192];
  __shared__ float sM2[4096];
  __shared__ float xs[16][68];
  __shared__ float xh[16][68];
  __shared__ float xq[16][68];
  for (int i = threadIdx.x; i < 4096; i += 256) {
    sR[i] = Wro1[i]; sG[i] = Wg[i]; sRo2[i] = Wro2[i]; sM2[i] = Wmlp2[i];
  }
  for (int i = threadIdx.x; i < 8192; i += 256) sM1[i] = Wmlp1[i];
  int nb = blockIdx.x * 16;
  for (int i = threadIdx.x; i < 1024; i += 256) {
    xs[i >> 6][i & 63] = nf0[(size_t)nb * 64 + i];
    xh[i >> 6][i & 63] = h[(size_t)nb * 64 + i];
  }
  __syncthreads();

  int lane = threadIdx.x & 63, w = threadIdx.x >> 6;
  int q = lane >> 4, c16 = lane & 15;
  int nloc = w * 4 + q;
  int n = nb + nloc;
  int col0 = c16 * 4;

  float qa0 = 0, qa1 = 0, qa2 = 0, qa3 = 0;
  float ga0 = 0, ga1 = 0, ga2 = 0, ga3 = 0;
  for (int m = 0; m < 64; ++m) {
    float x = xs[nloc][m];
    float4 wr = *(const float4*)&sR[m * 64 + col0];
    float4 wg = *(const float4*)&sG[m * 64 + col0];
    qa0 = fmaf(x, wr.x, qa0); qa1 = fmaf(x, wr.y, qa1);
    qa2 = fmaf(x, wr.z, qa2); qa3 = fmaf(x, wr.w, qa3);
    ga0 = fmaf(x, wg.x, ga0); ga1 = fmaf(x, wg.y, ga1);
    ga2 = fmaf(x, wg.z, ga2); ga3 = fmaf(x, wg.w, ga3);
  }
  float4 b1v = *(const float4*)&bro1[col0];
  float q0 = silu_f(qa0 + b1v.x), q1 = silu_f(qa1 + b1v.y);
  float q2 = silu_f(qa2 + b1v.z), q3 = silu_f(qa3 + b1v.w);
  float g0 = silu_f(ga0), g1 = silu_f(ga1), g2 = silu_f(ga2), g3 = silu_f(ga3);

  {
    float4 wv4 = *(const float4*)&wvv[col0];
    const float4* v3p = (const float4*)&v3[(size_t)n * 192 + col0 * 3];
    float4 va = v3p[0], vb = v3p[1], vc = v3p[2];
    float gw0 = g0 * wv4.x, gw1 = g1 * wv4.y, gw2 = g2 * wv4.z, gw3 = g3 * wv4.w;
    float p0 = va.x * gw0 + va.w * gw1 + vb.z * gw2 + vc.y * gw3;
    float p1 = va.y * gw0 + vb.x * gw1 + vb.w * gw2 + vc.z * gw3;
    float p2 = va.z * gw0 + vb.y * gw1 + vc.x * gw2 + vc.w * gw3;
#pragma unroll
    for (int m = 1; m < 16; m <<= 1) {
      p0 += __shfl_xor(p0, m);
      p1 += __shfl_xor(p1, m);
      p2 += __shfl_xor(p2, m);
    }
    if (c16 == 0) {
      pos[n * 3 + 0] += p0;
      pos[n * 3 + 1] += p1;
      pos[n * 3 + 2] += p2;
    }
  }

  *(float4*)&xq[nloc][col0] = make_float4(q0, q1, q2, q3);
  float s20 = 0, s21 = 0, s22 = 0, s23 = 0;
  for (int m = 0; m < 64; ++m) {
    float x = xq[nloc][m];
    float4 w2 = *(const float4*)&sRo2[m * 64 + col0];
    s20 = fmaf(x, w2.x, s20); s21 = fmaf(x, w2.y, s21);
    s22 = fmaf(x, w2.z, s22); s23 = fmaf(x, w2.w, s23);
  }
  *(float4*)&xs[nloc][col0] = make_float4(s20, s21, s22, s23);

  float4 bm1 = *(const float4*)&bmlp1[col0];
  float u0 = bm1.x, u1 = bm1.y, u2 = bm1.z, u3 = bm1.w;
  for (int m = 0; m < 64; ++m) {
    float xm = xh[nloc][m];
    float4 m1 = *(const float4*)&sM1[m * 64 + col0];
    u0 = fmaf(xm, m1.x, u0); u1 = fmaf(xm, m1.y, u1);
    u2 = fmaf(xm, m1.z, u2); u3 = fmaf(xm, m1.w, u3);
  }
  for (int m = 0; m < 64; ++m) {
    float xm = xs[nloc][m];
    float4 m1 = *(const float4*)&sM1[(64 + m) * 64 + col0];
    u0 = fmaf(xm, m1.x, u0); u1 = fmaf(xm, m1.y, u1);
    u2 = fmaf(xm, m1.z, u2); u3 = fmaf(xm, m1.w, u3);
  }
  u0 = silu_f(u0); u1 = silu_f(u1); u2 = silu_f(u2); u3 = silu_f(u3);
  *(float4*)&xq[nloc][col0] = make_float4(u0, u1, u2, u3);

  float4 bm2 = *(const float4*)&bmlp2[col0];
  float4 hold = *(float4*)&xh[nloc][col0];
  float h0 = hold.x + bm2.x, h1 = hold.y + bm2.y;
  float h2 = hold.z + bm2.z, h3 = hold.w + bm2.w;
  for (int m = 0; m < 64; ++m) {
    float um = xq[nloc][m];
    float4 m2 = *(const float4*)&sM2[m * 64 + col0];
    h0 = fmaf(um, m2.x, h0); h1 = fmaf(um, m2.y, h1);
    h2 = fmaf(um, m2.z, h2); h3 = fmaf(um, m2.w, h3);
  }
  *(float4*)&h[(size_t)n * 64 + col0] = make_float4(h0, h1, h2, h3);
}

// ---------------- outputs ----------------
__global__ __launch_bounds__(256) void k_pred(
    const float* __restrict__ h, const float* __restrict__ Wout,
    const float* __restrict__ bout, float* __restrict__ out) {
  __shared__ float sW[704];
  for (int i = threadIdx.x; i < 704; i += 256) sW[i] = Wout[i];
  __syncthreads();
  int n = blockIdx.x * 256 + threadIdx.x;
  if (n >= NN) return;
  float acc[10];
#pragma unroll
  for (int j = 0; j < 10; ++j) acc[j] = bout[j];
  const float* row = h + (size_t)n * 64;
  for (int hh = 0; hh < 64; ++hh) {
    float hv = row[hh];
#pragma unroll
    for (int j = 0; j < 10; ++j) acc[j] = fmaf(hv, sW[hh * 11 + j], acc[j]);
  }
  float* orow = out + (size_t)n * 10;
#pragma unroll
  for (int j = 0; j < 10; ++j) orow[j] = acc[j];
}

__global__ __launch_bounds__(256) void k_batch(
    const int* __restrict__ batch, const float* __restrict__ pos,
    float* __restrict__ bacc) {
  int n = blockIdx.x * 256 + threadIdx.x;
  int lane = threadIdx.x & 63;
  bool valid = n < NN;
  int b = valid ? batch[n] : -1;
  float p0 = valid ? pos[n * 3 + 0] : 0.f;
  float p1 = valid ? pos[n * 3 + 1] : 0.f;
  float p2 = valid ? pos[n * 3 + 2] : 0.f;
  float c  = valid ? 1.f : 0.f;
#pragma unroll
  for (int d = 1; d < 64; d <<= 1) {
    float q0 = __shfl_down(p0, d);
    float q1 = __shfl_down(p1, d);
    float q2 = __shfl_down(p2, d);
    float qc = __shfl_down(c, d);
    int bd   = __shfl_down(b, d);
    if (lane + d < 64 && bd == b) { p0 += q0; p1 += q1; p2 += q2; c += qc; }
  }
  int bprev = __shfl_up(b, 1);
  bool head = valid && (lane == 0 || bprev != b);
  if (head) {
    atomicAdd(&bacc[b * 4 + 0], p0);
    atomicAdd(&bacc[b * 4 + 1], p1);
    atomicAdd(&bacc[b * 4 + 2], p2);
    atomicAdd(&bacc[b * 4 + 3], c);
  }
}

__global__ __launch_bounds__(256) void k_predpos(
    const int* __restrict__ batch, const float* __restrict__ pos,
    const float* __restrict__ pos0, const float* __restrict__ bacc,
    float* __restrict__ out) {
  int n = blockIdx.x * 256 + threadIdx.x;
  if (n >= NN) return;
  int b = batch[n];
  float cnt = fmaxf(bacc[b * 4 + 3], 1.0f);
#pragma unroll
  for (int c = 0; c < 3; ++c)
    out[NN * 10 + n * 3 + c] = pos[n * 3 + c] - bacc[b * 4 + c] / cnt - pos0[n * 3 + c];
}

extern "C" void kernel_launch(void* const* d_in, const int* in_sizes, int n_in,
                              void* d_out, int out_size, void* d_ws, size_t ws_size,
                              hipStream_t stream) {
  const float* positions = (const float*)d_in[0];
  const float* node_attrs = (const float*)d_in[1];
  const float* t_in = (const float*)d_in[2];
  const float* shifts = (const float*)d_in[3];
  const int* batch = (const int*)d_in[4];
  const int* edge_index = (const int*)d_in[5];
  const float* W_emb = (const float*)d_in[6];
  const float* b_emb = (const float*)d_in[7];
  const float* W_out = (const float*)d_in[8];
  const float* b_out = (const float*)d_in[9];
  const float* Wr1 = (const float*)d_in[10];
  const float* br1 = (const float*)d_in[11];
  const float* Wr2 = (const float*)d_in[12];
  const float* W_up = (const float*)d_in[13];
  const float* W_mix = (const float*)d_in[14];
  const float* W_prod = (const float*)d_in[15];
  const float* Wro1 = (const float*)d_in[16];
  const float* bro1 = (const float*)d_in[17];
  const float* Wro2 = (const float*)d_in[18];
  const float* Wg = (const float*)d_in[19];
  const float* wv = (const float*)d_in[20];
  const float* Wmlp1 = (const float*)d_in[21];
  const float* bmlp1 = (const float*)d_in[22];
  const float* Wmlp2 = (const float*)d_in[23];
  const float* bmlp2 = (const float*)d_in[24];

  float* ws = (float*)d_ws;
  float* pos_cur = ws + OFF_POS;
  float* hbuf    = ws + OFF_H;
  float* nf0     = ws + OFF_NF0;
  float* nfup0   = ws + OFF_NUP;
  float* v3      = ws + OFF_V3;
  float* table   = ws + OFF_TAB;
  float4* agg    = (float4*)(ws + OFF_AGG);
  float* w_s     = ws + OFF_WW;
  float4* y_s    = (float4*)(ws + OFF_WY);
  int* eslot     = (int*)(ws + OFF_ESLOT);
  int* csroff    = (int*)(ws + OFF_CSR);
  int* counts    = (int*)(ws + OFF_CNT);
  int* cursor    = (int*)(ws + OFF_CUR);
  float* bacc    = ws + OFF_BACC;
  int* maxlen    = (int*)(ws + OFF_MAXL);

  hipMemsetAsync(counts, 0, (WS_END - OFF_CNT) * sizeof(float), stream);

  k_embed_count_up<<<3125, 256, 0, stream>>>(positions, node_attrs, t_in, batch,
                                             W_emb, b_emb, W_up,
                                             hbuf, nf0, pos_cur, nfup0,
                                             edge_index, counts);
  k_scan<<<1, 1024, 0, stream>>>(counts, csroff);
  k_scatter<<<625, 256, 0, stream>>>(edge_index, csroff, cursor, eslot);

  for (int i = 0; i < 2; ++i) {
    hipMemsetAsync(maxlen, 0, 4, stream);
    k_maxlen<<<625, 256, 0, stream>>>(edge_index, shifts, pos_cur, maxlen);
    k_table<<<1024, 256, 0, stream>>>(Wr1 + i * 64, br1 + i * 64, Wr2 + i * 4096,
                                      maxlen, table);
    k_edge<<<625, 256, 0, stream>>>(edge_index, shifts, pos_cur, nfup0,
                                    eslot, (const float4*)table, maxlen,
                                    w_s, y_s);
    k_gather<<<2500, 256, 0, stream>>>(csroff, w_s, y_s, agg);
    k_mix_prod<<<625, 256, 0, stream>>>(agg, W_mix + i * 4096, W_prod + i * 4096,
                                        nf0, v3,
                                        (i == 0) ? (W_up + 4096) : nullptr, nfup0);
    k_readout_mlp<<<625, 256, 0, stream>>>(nf0, v3, Wro1 + i * 4096, bro1 + i * 64,
                                           Wg + i * 4096, wv + i * 64,
                                           Wro2 + i * 4096,
                                           Wmlp1 + i * 8192, bmlp1 + i * 64,
                                           Wmlp2 + i * 4096, bmlp2 + i * 64,
                                           pos_cur, hbuf);
  }

  k_pred<<<40, 256, 0, stream>>>(hbuf, W_out, b_out, (float*)d_out);
  k_batch<<<40, 256, 0, stream>>>(batch, pos_cur, bacc);
  k_predpos<<<40, 256, 0, stream>>>(batch, pos_cur, positions, bacc, (float*)d_out);
}

// Round 14
// 360.450 us; speedup vs baseline: 1.1977x; 1.1977x over previous
//
#include <hip/hip_runtime.h>

#define NN 10000
#define NEDGE 160000
#define NBATCH 64

// ---------------- workspace layout (units: floats) ----------------
static constexpr size_t OFF_POS   = 0;                     // N*3 (pad 30016)
static constexpr size_t OFF_H     = 30016;                 // N*64
static constexpr size_t OFF_NF0   = 670016;                // N*64
static constexpr size_t OFF_NUP   = 1310016;               // N*64
static constexpr size_t OFF_V3    = 1950016;               // N*192
static constexpr size_t OFF_TAB   = 3870016;               // 2 layers * 4096*64
static constexpr size_t OFF_AGG   = 4394304;               // N*256 (float4[N*64])
static constexpr size_t OFF_EL    = 6954304;               // E ints (CSR edge list)
static constexpr size_t OFF_CSR   = 7114304;               // N+1 ints (pad 10016)
static constexpr size_t OFF_CNT   = 7124320;               // N ints
static constexpr size_t OFF_CUR   = 7134336;               // N ints
static constexpr size_t OFF_BACC  = 7144352;               // B*4 floats
static constexpr size_t WS_END    = 7144608;

__device__ __forceinline__ float silu_f(float x) {
  return x / (1.0f + __expf(-x));
}

// ---------------- setup ----------------
__global__ __launch_bounds__(256) void k_embed_count_up(
    const float* __restrict__ pos_in, const float* __restrict__ na,
    const float* __restrict__ t, const int* __restrict__ batch,
    const float* __restrict__ Wemb, const float* __restrict__ bemb,
    const float* __restrict__ Wup0,
    float* __restrict__ h, float* __restrict__ nf0, float* __restrict__ pos_cur,
    float* __restrict__ nfup0,
    const int* __restrict__ ei, int* __restrict__ counts) {
  if (blockIdx.x >= 2500) {
    int e = (blockIdx.x - 2500) * 256 + threadIdx.x;   // exactly E threads
    atomicAdd(&counts[ei[NEDGE + e]], 1);
    return;
  }
  __shared__ float sx[4][64];
  int tid = blockIdx.x * 256 + threadIdx.x;   // exactly N*64 threads
  int n = tid >> 6, k = tid & 63;
  int w = threadIdx.x >> 6;
  float acc = bemb[k];
  const float* arow = na + n * 10;
#pragma unroll
  for (int j = 0; j < 10; ++j)
    acc = fmaf(arow[j] * 0.25f, Wemb[j * 64 + k], acc);
  acc = fmaf(t[batch[n]], Wemb[10 * 64 + k], acc);
  h[tid] = acc;
  nf0[tid] = acc;
  if (k < 3) pos_cur[n * 3 + k] = pos_in[n * 3 + k];
  sx[w][k] = acc;
  __syncthreads();
  float up = 0.f;
  for (int hh = 0; hh < 64; ++hh)
    up = fmaf(sx[w][hh], Wup0[hh * 64 + k], up);
  nfup0[tid] = up;
}

__global__ __launch_bounds__(1024) void k_scan(const int* __restrict__ counts,
                                               int* __restrict__ offs) {
  __shared__ int part[1024];
  int tid = threadIdx.x;
  int base = tid * 10;
  int local[10];
  int s = 0;
#pragma unroll
  for (int j = 0; j < 10; ++j) {
    int idx = base + j;
    int v = (idx < NN) ? counts[idx] : 0;
    local[j] = s;
    s += v;
  }
  part[tid] = s;
  __syncthreads();
  for (int d = 1; d < 1024; d <<= 1) {
    int v = (tid >= d) ? part[tid - d] : 0;
    __syncthreads();
    part[tid] += v;
    __syncthreads();
  }
  int excl = (tid == 0) ? 0 : part[tid - 1];
#pragma unroll
  for (int j = 0; j < 10; ++j) {
    int idx = base + j;
    if (idx < NN) offs[idx] = excl + local[j];
  }
  if (tid == 1023) offs[NN] = excl + s;
}

// CSR edge list: edgelist[offs[r] + cnt] = e  (edges grouped by rcv)
__global__ __launch_bounds__(256) void k_scatter(
    const int* __restrict__ ei, const int* __restrict__ offs,
    int* __restrict__ cursor, int* __restrict__ edgelist) {
  int e = blockIdx.x * 256 + threadIdx.x;
  int r = ei[NEDGE + e];
  int slot = atomicAdd(&cursor[r], 1);
  edgelist[offs[r] + slot] = e;
}

// ---------------- r-tables (both layers, log2-indexed, built once) ----------
// row rr in [0,4096): binade eb=rr>>5 (e = eb-64), mantissa step kk=rr&31;
// len_s = ldexp(0.5 + kk/64, eb-64). Lerp in mantissa == lerp in len.
__global__ __launch_bounds__(256) void k_tables(
    const float* __restrict__ Wr1, const float* __restrict__ br1,
    const float* __restrict__ Wr2, float* __restrict__ table) {
  __shared__ float sl[4][64];
  int si = threadIdx.x >> 6, hh = threadIdx.x & 63;
  int row = blockIdx.x * 4 + si;        // grid 2048 -> 8192 rows (2 layers)
  int l = row >> 12;
  int rr = row & 4095;
  int eb = rr >> 5, kk = rr & 31;
  float len_s = ldexpf(0.5f + (float)kk * (1.0f / 64.0f), eb - 64);
  sl[si][hh] = silu_f(fmaf(len_s, Wr1[l * 64 + hh], br1[l * 64 + hh]));
  __syncthreads();
  const float* W2 = Wr2 + l * 4096;
  float acc = 0.f;
  for (int m = 0; m < 64; ++m)
    acc = fmaf(sl[si][m], W2[m * 64 + hh], acc);
  table[(size_t)row * 64 + hh] = acc;
}

// ---------------- fused message+aggregate (replaces k_edge + k_gather) -----
// Wave per node n walks its CSR edges: all edge geometry is wave-uniform
// (scalar path); table rows + nfup0 rows are coalesced 256B reads (L2-hot:
// table 1MB, nfup0 2.5MB). NO w_s/y_s round-trip -> kills the random-scatter
// HBM writes that pinned k_edge at ~56us (1.1TB/s scatter ceiling, r11 PMC).
__global__ __launch_bounds__(256) void k_msg(
    const int* __restrict__ ei, const float* __restrict__ shifts,
    const float* __restrict__ pos, const float* __restrict__ nfup0,
    const int* __restrict__ offs, const int* __restrict__ edgelist,
    const float* __restrict__ tab, float4* __restrict__ agg) {
  int n = blockIdx.x * 4 + (threadIdx.x >> 6);   // grid 2500 -> 10000 nodes
  int lane = threadIdx.x & 63;
  int beg = offs[n], end = offs[n + 1];
  float px = pos[n * 3 + 0], py = pos[n * 3 + 1], pz = pos[n * 3 + 2];
  float a0 = 0.f, a1 = 0.f, a2 = 0.f, a3 = 0.f;
  const float c1 = 1.7320508f * 0.0625f;         // sqrt(3)/AVG_NEIGH
  for (int j = beg; j < end; ++j) {
    int el = edgelist[j];
    int s = ei[el];
    float vx = px - pos[s * 3 + 0] + shifts[el * 3 + 0];
    float vy = py - pos[s * 3 + 1] + shifts[el * 3 + 1];
    float vz = pz - pos[s * 3 + 2] + shifts[el * 3 + 2];
    float len = sqrtf(vx * vx + vy * vy + vz * vz);
    float inv = 1.0f / (len + 1e-9f);
    float y1 = c1 * vx * inv, y2 = c1 * vy * inv, y3 = c1 * vz * inv;
    int ebin; float m = frexpf(len, &ebin);
    float t = (m - 0.5f) * 64.0f;                // [0,32)
    int ti = (int)t;
    float fr = t - (float)ti;
    int eb = ebin + 64; eb = eb < 0 ? 0 : (eb > 127 ? 127 : eb);
    int row = eb * 32 + ti;
    if (!(len > 0.0f)) { row = 0; fr = 0.0f; }
    int row1 = row + 1 > 4095 ? 4095 : row + 1;
    float ta = tab[(size_t)row * 64 + lane];
    float tb = tab[(size_t)row1 * 64 + lane];
    float w = fmaf(fr, tb - ta, ta) * nfup0[(size_t)s * 64 + lane];
    a0 = fmaf(w, 0.0625f, a0);
    a1 = fmaf(w, y1, a1);
    a2 = fmaf(w, y2, a2);
    a3 = fmaf(w, y3, a3);
  }
  agg[(size_t)n * 64 + lane] = make_float4(a0, a1, a2, a3);
}

// k_mix_prod v2 (unchanged from round 8)
__global__ __launch_bounds__(256) void k_mix_prod(
    const float4* __restrict__ agg, const float* __restrict__ Wmix,
    const float* __restrict__ Wprod, float* __restrict__ nf0,
    float* __restrict__ v3, const float* __restrict__ Wup_next,
    float* __restrict__ nfup0) {
  __shared__ float sMix[4096];
  __shared__ float sProd[4096];
  __shared__ float sUp[4096];
  __shared__ float4 xa[16][65];
  for (int i = threadIdx.x; i < 4096; i += 256) { sMix[i] = Wmix[i]; sProd[i] = Wprod[i]; }
  if (Wup_next)
    for (int i = threadIdx.x; i < 4096; i += 256) sUp[i] = Wup_next[i];
  int nb = blockIdx.x * 16;
  for (int i = threadIdx.x; i < 1024; i += 256)
    xa[i >> 6][i & 63] = agg[(size_t)nb * 64 + i];
  __syncthreads();

  int lane = threadIdx.x & 63, w = threadIdx.x >> 6;
  int q = lane >> 4, c16 = lane & 15;
  int nloc = w * 4 + q;
  int n = nb + nloc;
  int col0 = c16 * 4;

  float4 a0 = {0,0,0,0}, a1 = {0,0,0,0}, a2 = {0,0,0,0}, a3 = {0,0,0,0};
  for (int hh = 0; hh < 64; ++hh) {
    float4 xv = xa[nloc][hh];
    float4 wm = *(const float4*)&sMix[hh * 64 + col0];
    a0.x = fmaf(xv.x, wm.x, a0.x); a0.y = fmaf(xv.y, wm.x, a0.y);
    a0.z = fmaf(xv.z, wm.x, a0.z); a0.w = fmaf(xv.w, wm.x, a0.w);
    a1.x = fmaf(xv.x, wm.y, a1.x); a1.y = fmaf(xv.y, wm.y, a1.y);
    a1.z = fmaf(xv.z, wm.y, a1.z); a1.w = fmaf(xv.w, wm.y, a1.w);
    a2.x = fmaf(xv.x, wm.z, a2.x); a2.y = fmaf(xv.y, wm.z, a2.y);
    a2.z = fmaf(xv.z, wm.z, a2.z); a2.w = fmaf(xv.w, wm.z, a2.w);
    a3.x = fmaf(xv.x, wm.w, a3.x); a3.y = fmaf(xv.y, wm.w, a3.y);
    a3.z = fmaf(xv.z, wm.w, a3.z); a3.w = fmaf(xv.w, wm.w, a3.w);
  }
  {
    float s0 = a0.x, f0 = 1.0f + s0 + s0 * s0;
    float s1 = a1.x, f1 = 1.0f + s1 + s1 * s1;
    float s2 = a2.x, f2 = 1.0f + s2 + s2 * s2;
    float s3 = a3.x, f3 = 1.0f + s3 + s3 * s3;
    a0.x *= f0; a0.y *= f0; a0.z *= f0; a0.w *= f0;
    a1.x *= f1; a1.y *= f1; a1.z *= f1; a1.w *= f1;
    a2.x *= f2; a2.y *= f2; a2.z *= f2; a2.w *= f2;
    a3.x *= f3; a3.y *= f3; a3.z *= f3; a3.w *= f3;
  }
  xa[nloc][col0 + 0] = a0; xa[nloc][col0 + 1] = a1;
  xa[nloc][col0 + 2] = a2; xa[nloc][col0 + 3] = a3;

  float4 p0 = {0,0,0,0}, p1 = {0,0,0,0}, p2 = {0,0,0,0}, p3 = {0,0,0,0};
  for (int hh = 0; hh < 64; ++hh) {
    float4 xv = xa[nloc][hh];
    float4 wm = *(const float4*)&sProd[hh * 64 + col0];
    p0.x = fmaf(xv.x, wm.x, p0.x); p0.y = fmaf(xv.y, wm.x, p0.y);
    p0.z = fmaf(xv.z, wm.x, p0.z); p0.w = fmaf(xv.w, wm.x, p0.w);
    p1.x = fmaf(xv.x, wm.y, p1.x); p1.y = fmaf(xv.y, wm.y, p1.y);
    p1.z = fmaf(xv.z, wm.y, p1.z); p1.w = fmaf(xv.w, wm.y, p1.w);
    p2.x = fmaf(xv.x, wm.z, p2.x); p2.y = fmaf(xv.y, wm.z, p2.y);
    p2.z = fmaf(xv.z, wm.z, p2.z); p2.w = fmaf(xv.w, wm.z, p2.w);
    p3.x = fmaf(xv.x, wm.w, p3.x); p3.y = fmaf(xv.y, wm.w, p3.y);
    p3.z = fmaf(xv.z, wm.w, p3.z); p3.w = fmaf(xv.w, wm.w, p3.w);
  }
  *(float4*)&nf0[(size_t)n * 64 + col0] = make_float4(p0.x, p1.x, p2.x, p3.x);
  {
    float4* v3p = (float4*)&v3[(size_t)n * 192 + col0 * 3];
    v3p[0] = make_float4(p0.y, p0.z, p0.w, p1.y);
    v3p[1] = make_float4(p1.z, p1.w, p2.y, p2.z);
    v3p[2] = make_float4(p2.w, p3.y, p3.z, p3.w);
  }
  if (Wup_next) {
    xa[nloc][col0 + 0] = p0; xa[nloc][col0 + 1] = p1;
    xa[nloc][col0 + 2] = p2; xa[nloc][col0 + 3] = p3;
    float u0 = 0.f, u1 = 0.f, u2 = 0.f, u3 = 0.f;
    for (int hh = 0; hh < 64; ++hh) {
      float xs = xa[nloc][hh].x;
      float4 wu = *(const float4*)&sUp[hh * 64 + col0];
      u0 = fmaf(xs, wu.x, u0); u1 = fmaf(xs, wu.y, u1);
      u2 = fmaf(xs, wu.z, u2); u3 = fmaf(xs, wu.w, u3);
    }
    *(float4*)&nfup0[(size_t)n * 64 + col0] = make_float4(u0, u1, u2, u3);
  }
}

// k_readout_mlp v2 (unchanged from round 8)
__global__ __launch_bounds__(256) void k_readout_mlp(
    const float* __restrict__ nf0, const float* __restrict__ v3,
    const float* __restrict__ Wro1, const float* __restrict__ bro1,
    const float* __restrict__ Wg, const float* __restrict__ wvv,
    const float* __restrict__ Wro2,
    const float* __restrict__ Wmlp1, const float* __restrict__ bmlp1,
    const float* __restrict__ Wmlp2, const float* __restrict__ bmlp2,
    float* __restrict__ pos, float* __restrict__ h) {
  __shared__ float sR[4096];
  __shared__ float sG[4096];
  __shared__ float sRo2[4096];
  __shared__ float sM1[8192];
  __shared__ float sM2[4096];
  __shared__ float xs[16][68];
  __shared__ float xh[16][68];
  __shared__ float xq[16][68];
  for (int i = threadIdx.x; i < 4096; i += 256) {
    sR[i] = Wro1[i]; sG[i] = Wg[i]; sRo2[i] = Wro2[i]; sM2[i] = Wmlp2[i];
  }
  for (int i = threadIdx.x; i < 8192; i += 256) sM1[i] = Wmlp1[i];
  int nb = blockIdx.x * 16;
  for (int i = threadIdx.x; i < 1024; i += 256) {
    xs[i >> 6][i & 63] = nf0[(size_t)nb * 64 + i];
    xh[i >> 6][i & 63] = h[(size_t)nb * 64 + i];
  }
  __syncthreads();

  int lane = threadIdx.x & 63, w = threadIdx.x >> 6;
  int q = lane >> 4, c16 = lane & 15;
  int nloc = w * 4 + q;
  int n = nb + nloc;
  int col0 = c16 * 4;

  float qa0 = 0, qa1 = 0, qa2 = 0, qa3 = 0;
  float ga0 = 0, ga1 = 0, ga2 = 0, ga3 = 0;
  for (int m = 0; m < 64; ++m) {
    float x = xs[nloc][m];
    float4 wr = *(const float4*)&sR[m * 64 + col0];
    float4 wg = *(const float4*)&sG[m * 64 + col0];
    qa0 = fmaf(x, wr.x, qa0); qa1 = fmaf(x, wr.y, qa1);
    qa2 = fmaf(x, wr.z, qa2); qa3 = fmaf(x, wr.w, qa3);
    ga0 = fmaf(x, wg.x, ga0); ga1 = fmaf(x, wg.y, ga1);
    ga2 = fmaf(x, wg.z, ga2); ga3 = fmaf(x, wg.w, ga3);
  }
  float4 b1v = *(const float4*)&bro1[col0];
  float q0 = silu_f(qa0 + b1v.x), q1 = silu_f(qa1 + b1v.y);
  float q2 = silu_f(qa2 + b1v.z), q3 = silu_f(qa3 + b1v.w);
  float g0 = silu_f(ga0), g1 = silu_f(ga1), g2 = silu_f(ga2), g3 = silu_f(ga3);

  {
    float4 wv4 = *(const float4*)&wvv[col0];
    const float4* v3p = (const float4*)&v3[(size_t)n * 192 + col0 * 3];
    float4 va = v3p[0], vb = v3p[1], vc = v3p[2];
    float gw0 = g0 * wv4.x, gw1 = g1 * wv4.y, gw2 = g2 * wv4.z, gw3 = g3 * wv4.w;
    float p0 = va.x * gw0 + va.w * gw1 + vb.z * gw2 + vc.y * gw3;
    float p1 = va.y * gw0 + vb.x * gw1 + vb.w * gw2 + vc.z * gw3;
    float p2 = va.z * gw0 + vb.y * gw1 + vc.x * gw2 + vc.w * gw3;
#pragma unroll
    for (int m = 1; m < 16; m <<= 1) {
      p0 += __shfl_xor(p0, m);
      p1 += __shfl_xor(p1, m);
      p2 += __shfl_xor(p2, m);
    }
    if (c16 == 0) {
      pos[n * 3 + 0] += p0;
      pos[n * 3 + 1] += p1;
      pos[n * 3 + 2] += p2;
    }
  }

  *(float4*)&xq[nloc][col0] = make_float4(q0, q1, q2, q3);
  float s20 = 0, s21 = 0, s22 = 0, s23 = 0;
  for (int m = 0; m < 64; ++m) {
    float x = xq[nloc][m];
    float4 w2 = *(const float4*)&sRo2[m * 64 + col0];
    s20 = fmaf(x, w2.x, s20); s21 = fmaf(x, w2.y, s21);
    s22 = fmaf(x, w2.z, s22); s23 = fmaf(x, w2.w, s23);
  }
  *(float4*)&xs[nloc][col0] = make_float4(s20, s21, s22, s23);

  float4 bm1 = *(const float4*)&bmlp1[col0];
  float u0 = bm1.x, u1 = bm1.y, u2 = bm1.z, u3 = bm1.w;
  for (int m = 0; m < 64; ++m) {
    float xm = xh[nloc][m];
    float4 m1 = *(const float4*)&sM1[m * 64 + col0];
    u0 = fmaf(xm, m1.x, u0); u1 = fmaf(xm, m1.y, u1);
    u2 = fmaf(xm, m1.z, u2); u3 = fmaf(xm, m1.w, u3);
  }
  for (int m = 0; m < 64; ++m) {
    float xm = xs[nloc][m];
    float4 m1 = *(const float4*)&sM1[(64 + m) * 64 + col0];
    u0 = fmaf(xm, m1.x, u0); u1 = fmaf(xm, m1.y, u1);
    u2 = fmaf(xm, m1.z, u2); u3 = fmaf(xm, m1.w, u3);
  }
  u0 = silu_f(u0); u1 = silu_f(u1); u2 = silu_f(u2); u3 = silu_f(u3);
  *(float4*)&xq[nloc][col0] = make_float4(u0, u1, u2, u3);

  float4 bm2 = *(const float4*)&bmlp2[col0];
  float4 hold = *(float4*)&xh[nloc][col0];
  float h0 = hold.x + bm2.x, h1 = hold.y + bm2.y;
  float h2 = hold.z + bm2.z, h3 = hold.w + bm2.w;
  for (int m = 0; m < 64; ++m) {
    float um = xq[nloc][m];
    float4 m2 = *(const float4*)&sM2[m * 64 + col0];
    h0 = fmaf(um, m2.x, h0); h1 = fmaf(um, m2.y, h1);
    h2 = fmaf(um, m2.z, h2); h3 = fmaf(um, m2.w, h3);
  }
  *(float4*)&h[(size_t)n * 64 + col0] = make_float4(h0, h1, h2, h3);
}

// ---------------- outputs ----------------
__global__ __launch_bounds__(256) void k_pred(
    const float* __restrict__ h, const float* __restrict__ Wout,
    const float* __restrict__ bout, float* __restrict__ out) {
  __shared__ float sW[704];
  for (int i = threadIdx.x; i < 704; i += 256) sW[i] = Wout[i];
  __syncthreads();
  int n = blockIdx.x * 256 + threadIdx.x;
  if (n >= NN) return;
  float acc[10];
#pragma unroll
  for (int j = 0; j < 10; ++j) acc[j] = bout[j];
  const float* row = h + (size_t)n * 64;
  for (int hh = 0; hh < 64; ++hh) {
    float hv = row[hh];
#pragma unroll
    for (int j = 0; j < 10; ++j) acc[j] = fmaf(hv, sW[hh * 11 + j], acc[j]);
  }
  float* orow = out + (size_t)n * 10;
#pragma unroll
  for (int j = 0; j < 10; ++j) orow[j] = acc[j];
}

__global__ __launch_bounds__(256) void k_batch(
    const int* __restrict__ batch, const float* __restrict__ pos,
    float* __restrict__ bacc) {
  int n = blockIdx.x * 256 + threadIdx.x;
  int lane = threadIdx.x & 63;
  bool valid = n < NN;
  int b = valid ? batch[n] : -1;
  float p0 = valid ? pos[n * 3 + 0] : 0.f;
  float p1 = valid ? pos[n * 3 + 1] : 0.f;
  float p2 = valid ? pos[n * 3 + 2] : 0.f;
  float c  = valid ? 1.f : 0.f;
#pragma unroll
  for (int d = 1; d < 64; d <<= 1) {
    float q0 = __shfl_down(p0, d);
    float q1 = __shfl_down(p1, d);
    float q2 = __shfl_down(p2, d);
    float qc = __shfl_down(c, d);
    int bd   = __shfl_down(b, d);
    if (lane + d < 64 && bd == b) { p0 += q0; p1 += q1; p2 += q2; c += qc; }
  }
  int bprev = __shfl_up(b, 1);
  bool head = valid && (lane == 0 || bprev != b);
  if (head) {
    atomicAdd(&bacc[b * 4 + 0], p0);
    atomicAdd(&bacc[b * 4 + 1], p1);
    atomicAdd(&bacc[b * 4 + 2], p2);
    atomicAdd(&bacc[b * 4 + 3], c);
  }
}

__global__ __launch_bounds__(256) void k_predpos(
    const int* __restrict__ batch, const float* __restrict__ pos,
    const float* __restrict__ pos0, const float* __restrict__ bacc,
    float* __restrict__ out) {
  int n = blockIdx.x * 256 + threadIdx.x;
  if (n >= NN) return;
  int b = batch[n];
  float cnt = fmaxf(bacc[b * 4 + 3], 1.0f);
#pragma unroll
  for (int c = 0; c < 3; ++c)
    out[NN * 10 + n * 3 + c] = pos[n * 3 + c] - bacc[b * 4 + c] / cnt - pos0[n * 3 + c];
}

extern "C" void kernel_launch(void* const* d_in, const int* in_sizes, int n_in,
                              void* d_out, int out_size, void* d_ws, size_t ws_size,
                              hipStream_t stream) {
  const float* positions = (const float*)d_in[0];
  const float* node_attrs = (const float*)d_in[1];
  const float* t_in = (const float*)d_in[2];
  const float* shifts = (const float*)d_in[3];
  const int* batch = (const int*)d_in[4];
  const int* edge_index = (const int*)d_in[5];
  const float* W_emb = (const float*)d_in[6];
  const float* b_emb = (const float*)d_in[7];
  const float* W_out = (const float*)d_in[8];
  const float* b_out = (const float*)d_in[9];
  const float* Wr1 = (const float*)d_in[10];
  const float* br1 = (const float*)d_in[11];
  const float* Wr2 = (const float*)d_in[12];
  const float* W_up = (const float*)d_in[13];
  const float* W_mix = (const float*)d_in[14];
  const float* W_prod = (const float*)d_in[15];
  const float* Wro1 = (const float*)d_in[16];
  const float* bro1 = (const float*)d_in[17];
  const float* Wro2 = (const float*)d_in[18];
  const float* Wg = (const float*)d_in[19];
  const float* wv = (const float*)d_in[20];
  const float* Wmlp1 = (const float*)d_in[21];
  const float* bmlp1 = (const float*)d_in[22];
  const float* Wmlp2 = (const float*)d_in[23];
  const float* bmlp2 = (const float*)d_in[24];

  float* ws = (float*)d_ws;
  float* pos_cur = ws + OFF_POS;
  float* hbuf    = ws + OFF_H;
  float* nf0     = ws + OFF_NF0;
  float* nfup0   = ws + OFF_NUP;
  float* v3      = ws + OFF_V3;
  float* table   = ws + OFF_TAB;
  float4* agg    = (float4*)(ws + OFF_AGG);
  int* edgelist  = (int*)(ws + OFF_EL);
  int* csroff    = (int*)(ws + OFF_CSR);
  int* counts    = (int*)(ws + OFF_CNT);
  int* cursor    = (int*)(ws + OFF_CUR);
  float* bacc    = ws + OFF_BACC;

  hipMemsetAsync(counts, 0, (WS_END - OFF_CNT) * sizeof(float), stream);

  k_embed_count_up<<<3125, 256, 0, stream>>>(positions, node_attrs, t_in, batch,
                                             W_emb, b_emb, W_up,
                                             hbuf, nf0, pos_cur, nfup0,
                                             edge_index, counts);
  k_scan<<<1, 1024, 0, stream>>>(counts, csroff);
  k_scatter<<<625, 256, 0, stream>>>(edge_index, csroff, cursor, edgelist);
  k_tables<<<2048, 256, 0, stream>>>(Wr1, br1, Wr2, table);

  for (int i = 0; i < 2; ++i) {
    k_msg<<<2500, 256, 0, stream>>>(edge_index, shifts, pos_cur, nfup0,
                                    csroff, edgelist,
                                    table + (size_t)i * 262144, agg);
    k_mix_prod<<<625, 256, 0, stream>>>(agg, W_mix + i * 4096, W_prod + i * 4096,
                                        nf0, v3,
                                        (i == 0) ? (W_up + 4096) : nullptr, nfup0);
    k_readout_mlp<<<625, 256, 0, stream>>>(nf0, v3, Wro1 + i * 4096, bro1 + i * 64,
                                           Wg + i * 4096, wv + i * 64,
                                           Wro2 + i * 4096,
                                           Wmlp1 + i * 8192, bmlp1 + i * 64,
                                           Wmlp2 + i * 4096, bmlp2 + i * 64,
                                           pos_cur, hbuf);
  }

  k_pred<<<40, 256, 0, stream>>>(hbuf, W_out, b_out, (float*)d_out);
  k_batch<<<40, 256, 0, stream>>>(batch, pos_cur, bacc);
  k_predpos<<<40, 256, 0, stream>>>(batch, pos_cur, positions, bacc, (float*)d_out);
}

// Round 15
// 323.782 us; speedup vs baseline: 1.3333x; 1.1132x over previous
//
#include <hip/hip_runtime.h>

#define NN 10000
#define NEDGE 160000
#define NBATCH 64

// ---------------- workspace layout (units: floats) ----------------
static constexpr size_t OFF_POS   = 0;                     // N*3 (pad 30016)
static constexpr size_t OFF_H     = 30016;                 // N*64
static constexpr size_t OFF_NF0   = 670016;                // N*64
static constexpr size_t OFF_NUP   = 1310016;               // N*64
static constexpr size_t OFF_V3    = 1950016;               // N*192
static constexpr size_t OFF_TAB   = 3870016;               // 2 layers * 4096*64
static constexpr size_t OFF_AGG   = 4394304;               // N*256 (float4[N*64])
static constexpr size_t OFF_EL    = 6954304;               // E ints (CSR edge list)
static constexpr size_t OFF_CSR   = 7114304;               // N+1 ints (pad 10016)
static constexpr size_t OFF_CNT   = 7124320;               // N ints
static constexpr size_t OFF_CUR   = 7134336;               // N ints
static constexpr size_t OFF_BACC  = 7144352;               // B*4 floats
static constexpr size_t WS_END    = 7144608;

__device__ __forceinline__ float silu_f(float x) {
  return x / (1.0f + __expf(-x));
}

// ---------------- setup ----------------
__global__ __launch_bounds__(256) void k_embed_count_up(
    const float* __restrict__ pos_in, const float* __restrict__ na,
    const float* __restrict__ t, const int* __restrict__ batch,
    const float* __restrict__ Wemb, const float* __restrict__ bemb,
    const float* __restrict__ Wup0,
    float* __restrict__ h, float* __restrict__ nf0, float* __restrict__ pos_cur,
    float* __restrict__ nfup0,
    const int* __restrict__ ei, int* __restrict__ counts) {
  if (blockIdx.x >= 2500) {
    int e = (blockIdx.x - 2500) * 256 + threadIdx.x;   // exactly E threads
    atomicAdd(&counts[ei[NEDGE + e]], 1);
    return;
  }
  __shared__ float sx[4][64];
  int tid = blockIdx.x * 256 + threadIdx.x;   // exactly N*64 threads
  int n = tid >> 6, k = tid & 63;
  int w = threadIdx.x >> 6;
  float acc = bemb[k];
  const float* arow = na + n * 10;
#pragma unroll
  for (int j = 0; j < 10; ++j)
    acc = fmaf(arow[j] * 0.25f, Wemb[j * 64 + k], acc);
  acc = fmaf(t[batch[n]], Wemb[10 * 64 + k], acc);
  h[tid] = acc;
  nf0[tid] = acc;
  if (k < 3) pos_cur[n * 3 + k] = pos_in[n * 3 + k];
  sx[w][k] = acc;
  __syncthreads();
  float up = 0.f;
  for (int hh = 0; hh < 64; ++hh)
    up = fmaf(sx[w][hh], Wup0[hh * 64 + k], up);
  nfup0[tid] = up;
}

__global__ __launch_bounds__(1024) void k_scan(const int* __restrict__ counts,
                                               int* __restrict__ offs) {
  __shared__ int part[1024];
  int tid = threadIdx.x;
  int base = tid * 10;
  int local[10];
  int s = 0;
#pragma unroll
  for (int j = 0; j < 10; ++j) {
    int idx = base + j;
    int v = (idx < NN) ? counts[idx] : 0;
    local[j] = s;
    s += v;
  }
  part[tid] = s;
  __syncthreads();
  for (int d = 1; d < 1024; d <<= 1) {
    int v = (tid >= d) ? part[tid - d] : 0;
    __syncthreads();
    part[tid] += v;
    __syncthreads();
  }
  int excl = (tid == 0) ? 0 : part[tid - 1];
#pragma unroll
  for (int j = 0; j < 10; ++j) {
    int idx = base + j;
    if (idx < NN) offs[idx] = excl + local[j];
  }
  if (tid == 1023) offs[NN] = excl + s;
}

// CSR edge list: edgelist[offs[r] + cnt] = e  (edges grouped by rcv)
__global__ __launch_bounds__(256) void k_scatter(
    const int* __restrict__ ei, const int* __restrict__ offs,
    int* __restrict__ cursor, int* __restrict__ edgelist) {
  int e = blockIdx.x * 256 + threadIdx.x;
  int r = ei[NEDGE + e];
  int slot = atomicAdd(&cursor[r], 1);
  edgelist[offs[r] + slot] = e;
}

// ---------------- r-tables (both layers, log2-indexed, built once) ----------
__global__ __launch_bounds__(256) void k_tables(
    const float* __restrict__ Wr1, const float* __restrict__ br1,
    const float* __restrict__ Wr2, float* __restrict__ table) {
  __shared__ float sl[4][64];
  int si = threadIdx.x >> 6, hh = threadIdx.x & 63;
  int row = blockIdx.x * 4 + si;        // grid 2048 -> 8192 rows (2 layers)
  int l = row >> 12;
  int rr = row & 4095;
  int eb = rr >> 5, kk = rr & 31;
  float len_s = ldexpf(0.5f + (float)kk * (1.0f / 64.0f), eb - 64);
  sl[si][hh] = silu_f(fmaf(len_s, Wr1[l * 64 + hh], br1[l * 64 + hh]));
  __syncthreads();
  const float* W2 = Wr2 + l * 4096;
  float acc = 0.f;
  for (int m = 0; m < 64; ++m)
    acc = fmaf(sl[si][m], W2[m * 64 + hh], acc);
  table[(size_t)row * 64 + hh] = acc;
}

// ---------------- fused message+aggregate, 4-wide software pipeline --------
// r14 PMC: VGPR=20, VALU 36%, HBM 7%, occ 42% -> serial per-edge latency
// chain (edgelist -> ei -> pos -> table/nfup). Fix: process 4 edges per
// iteration; all index loads, then all geometry, then 12 independent row
// reads -> 4x memory-level parallelism on the chain.
__global__ __launch_bounds__(256) void k_msg(
    const int* __restrict__ ei, const float* __restrict__ shifts,
    const float* __restrict__ pos, const float* __restrict__ nfup0,
    const int* __restrict__ offs, const int* __restrict__ edgelist,
    const float* __restrict__ tab, float4* __restrict__ agg) {
  int n = blockIdx.x * 4 + (threadIdx.x >> 6);   // grid 2500 -> 10000 nodes
  int lane = threadIdx.x & 63;
  int beg = offs[n], end = offs[n + 1];
  float px = pos[n * 3 + 0], py = pos[n * 3 + 1], pz = pos[n * 3 + 2];
  float a0 = 0.f, a1 = 0.f, a2 = 0.f, a3 = 0.f;
  const float c1 = 1.7320508f * 0.0625f;         // sqrt(3)/AVG_NEIGH

  int j = beg;
  for (; j + 4 <= end; j += 4) {
    int el0 = edgelist[j + 0], el1 = edgelist[j + 1];
    int el2 = edgelist[j + 2], el3 = edgelist[j + 3];
    int s0 = ei[el0], s1 = ei[el1], s2 = ei[el2], s3 = ei[el3];

    float vx0 = px - pos[s0 * 3 + 0] + shifts[el0 * 3 + 0];
    float vy0 = py - pos[s0 * 3 + 1] + shifts[el0 * 3 + 1];
    float vz0 = pz - pos[s0 * 3 + 2] + shifts[el0 * 3 + 2];
    float vx1 = px - pos[s1 * 3 + 0] + shifts[el1 * 3 + 0];
    float vy1 = py - pos[s1 * 3 + 1] + shifts[el1 * 3 + 1];
    float vz1 = pz - pos[s1 * 3 + 2] + shifts[el1 * 3 + 2];
    float vx2 = px - pos[s2 * 3 + 0] + shifts[el2 * 3 + 0];
    float vy2 = py - pos[s2 * 3 + 1] + shifts[el2 * 3 + 1];
    float vz2 = pz - pos[s2 * 3 + 2] + shifts[el2 * 3 + 2];
    float vx3 = px - pos[s3 * 3 + 0] + shifts[el3 * 3 + 0];
    float vy3 = py - pos[s3 * 3 + 1] + shifts[el3 * 3 + 1];
    float vz3 = pz - pos[s3 * 3 + 2] + shifts[el3 * 3 + 2];

    float len0 = sqrtf(vx0 * vx0 + vy0 * vy0 + vz0 * vz0);
    float len1 = sqrtf(vx1 * vx1 + vy1 * vy1 + vz1 * vz1);
    float len2 = sqrtf(vx2 * vx2 + vy2 * vy2 + vz2 * vz2);
    float len3 = sqrtf(vx3 * vx3 + vy3 * vy3 + vz3 * vz3);
    float iv0 = 1.0f / (len0 + 1e-9f), iv1 = 1.0f / (len1 + 1e-9f);
    float iv2 = 1.0f / (len2 + 1e-9f), iv3 = 1.0f / (len3 + 1e-9f);

    int e0; float m0 = frexpf(len0, &e0);
    int e1; float m1 = frexpf(len1, &e1);
    int e2; float m2 = frexpf(len2, &e2);
    int e3; float m3 = frexpf(len3, &e3);
    float t0 = (m0 - 0.5f) * 64.0f, t1 = (m1 - 0.5f) * 64.0f;
    float t2 = (m2 - 0.5f) * 64.0f, t3 = (m3 - 0.5f) * 64.0f;
    int i0 = (int)t0, i1 = (int)t1, i2 = (int)t2, i3 = (int)t3;
    float f0 = t0 - (float)i0, f1 = t1 - (float)i1;
    float f2 = t2 - (float)i2, f3 = t3 - (float)i3;
    int b0 = e0 + 64; b0 = b0 < 0 ? 0 : (b0 > 127 ? 127 : b0);
    int b1 = e1 + 64; b1 = b1 < 0 ? 0 : (b1 > 127 ? 127 : b1);
    int b2 = e2 + 64; b2 = b2 < 0 ? 0 : (b2 > 127 ? 127 : b2);
    int b3 = e3 + 64; b3 = b3 < 0 ? 0 : (b3 > 127 ? 127 : b3);
    int r0 = b0 * 32 + i0, r1 = b1 * 32 + i1;
    int r2 = b2 * 32 + i2, r3 = b3 * 32 + i3;
    if (!(len0 > 0.0f)) { r0 = 0; f0 = 0.0f; }
    if (!(len1 > 0.0f)) { r1 = 0; f1 = 0.0f; }
    if (!(len2 > 0.0f)) { r2 = 0; f2 = 0.0f; }
    if (!(len3 > 0.0f)) { r3 = 0; f3 = 0.0f; }
    int r0b = r0 + 1 > 4095 ? 4095 : r0 + 1;
    int r1b = r1 + 1 > 4095 ? 4095 : r1 + 1;
    int r2b = r2 + 1 > 4095 ? 4095 : r2 + 1;
    int r3b = r3 + 1 > 4095 ? 4095 : r3 + 1;

    // 12 independent row reads issued together
    float ta0 = tab[(size_t)r0 * 64 + lane], tb0 = tab[(size_t)r0b * 64 + lane];
    float ta1 = tab[(size_t)r1 * 64 + lane], tb1 = tab[(size_t)r1b * 64 + lane];
    float ta2 = tab[(size_t)r2 * 64 + lane], tb2 = tab[(size_t)r2b * 64 + lane];
    float ta3 = tab[(size_t)r3 * 64 + lane], tb3 = tab[(size_t)r3b * 64 + lane];
    float u0 = nfup0[(size_t)s0 * 64 + lane];
    float u1 = nfup0[(size_t)s1 * 64 + lane];
    float u2 = nfup0[(size_t)s2 * 64 + lane];
    float u3 = nfup0[(size_t)s3 * 64 + lane];

    float w0 = fmaf(f0, tb0 - ta0, ta0) * u0;
    float w1 = fmaf(f1, tb1 - ta1, ta1) * u1;
    float w2 = fmaf(f2, tb2 - ta2, ta2) * u2;
    float w3 = fmaf(f3, tb3 - ta3, ta3) * u3;

    a0 = fmaf(w0, 0.0625f, a0);
    a1 = fmaf(w0, c1 * vx0 * iv0, a1);
    a2 = fmaf(w0, c1 * vy0 * iv0, a2);
    a3 = fmaf(w0, c1 * vz0 * iv0, a3);
    a0 = fmaf(w1, 0.0625f, a0);
    a1 = fmaf(w1, c1 * vx1 * iv1, a1);
    a2 = fmaf(w1, c1 * vy1 * iv1, a2);
    a3 = fmaf(w1, c1 * vz1 * iv1, a3);
    a0 = fmaf(w2, 0.0625f, a0);
    a1 = fmaf(w2, c1 * vx2 * iv2, a1);
    a2 = fmaf(w2, c1 * vy2 * iv2, a2);
    a3 = fmaf(w2, c1 * vz2 * iv2, a3);
    a0 = fmaf(w3, 0.0625f, a0);
    a1 = fmaf(w3, c1 * vx3 * iv3, a1);
    a2 = fmaf(w3, c1 * vy3 * iv3, a2);
    a3 = fmaf(w3, c1 * vz3 * iv3, a3);
  }
  for (; j < end; ++j) {
    int el = edgelist[j];
    int s = ei[el];
    float vx = px - pos[s * 3 + 0] + shifts[el * 3 + 0];
    float vy = py - pos[s * 3 + 1] + shifts[el * 3 + 1];
    float vz = pz - pos[s * 3 + 2] + shifts[el * 3 + 2];
    float len = sqrtf(vx * vx + vy * vy + vz * vz);
    float inv = 1.0f / (len + 1e-9f);
    int ebin; float m = frexpf(len, &ebin);
    float t = (m - 0.5f) * 64.0f;
    int ti = (int)t;
    float fr = t - (float)ti;
    int eb = ebin + 64; eb = eb < 0 ? 0 : (eb > 127 ? 127 : eb);
    int row = eb * 32 + ti;
    if (!(len > 0.0f)) { row = 0; fr = 0.0f; }
    int row1 = row + 1 > 4095 ? 4095 : row + 1;
    float ta = tab[(size_t)row * 64 + lane];
    float tb = tab[(size_t)row1 * 64 + lane];
    float w = fmaf(fr, tb - ta, ta) * nfup0[(size_t)s * 64 + lane];
    a0 = fmaf(w, 0.0625f, a0);
    a1 = fmaf(w, c1 * vx * inv, a1);
    a2 = fmaf(w, c1 * vy * inv, a2);
    a3 = fmaf(w, c1 * vz * inv, a3);
  }
  agg[(size_t)n * 64 + lane] = make_float4(a0, a1, a2, a3);
}

// k_mix_prod v2 (unchanged from round 8)
__global__ __launch_bounds__(256) void k_mix_prod(
    const float4* __restrict__ agg, const float* __restrict__ Wmix,
    const float* __restrict__ Wprod, float* __restrict__ nf0,
    float* __restrict__ v3, const float* __restrict__ Wup_next,
    float* __restrict__ nfup0) {
  __shared__ float sMix[4096];
  __shared__ float sProd[4096];
  __shared__ float sUp[4096];
  __shared__ float4 xa[16][65];
  for (int i = threadIdx.x; i < 4096; i += 256) { sMix[i] = Wmix[i]; sProd[i] = Wprod[i]; }
  if (Wup_next)
    for (int i = threadIdx.x; i < 4096; i += 256) sUp[i] = Wup_next[i];
  int nb = blockIdx.x * 16;
  for (int i = threadIdx.x; i < 1024; i += 256)
    xa[i >> 6][i & 63] = agg[(size_t)nb * 64 + i];
  __syncthreads();

  int lane = threadIdx.x & 63, w = threadIdx.x >> 6;
  int q = lane >> 4, c16 = lane & 15;
  int nloc = w * 4 + q;
  int n = nb + nloc;
  int col0 = c16 * 4;

  float4 a0 = {0,0,0,0}, a1 = {0,0,0,0}, a2 = {0,0,0,0}, a3 = {0,0,0,0};
  for (int hh = 0; hh < 64; ++hh) {
    float4 xv = xa[nloc][hh];
    float4 wm = *(const float4*)&sMix[hh * 64 + col0];
    a0.x = fmaf(xv.x, wm.x, a0.x); a0.y = fmaf(xv.y, wm.x, a0.y);
    a0.z = fmaf(xv.z, wm.x, a0.z); a0.w = fmaf(xv.w, wm.x, a0.w);
    a1.x = fmaf(xv.x, wm.y, a1.x); a1.y = fmaf(xv.y, wm.y, a1.y);
    a1.z = fmaf(xv.z, wm.y, a1.z); a1.w = fmaf(xv.w, wm.y, a1.w);
    a2.x = fmaf(xv.x, wm.z, a2.x); a2.y = fmaf(xv.y, wm.z, a2.y);
    a2.z = fmaf(xv.z, wm.z, a2.z); a2.w = fmaf(xv.w, wm.z, a2.w);
    a3.x = fmaf(xv.x, wm.w, a3.x); a3.y = fmaf(xv.y, wm.w, a3.y);
    a3.z = fmaf(xv.z, wm.w, a3.z); a3.w = fmaf(xv.w, wm.w, a3.w);
  }
  {
    float s0 = a0.x, f0 = 1.0f + s0 + s0 * s0;
    float s1 = a1.x, f1 = 1.0f + s1 + s1 * s1;
    float s2 = a2.x, f2 = 1.0f + s2 + s2 * s2;
    float s3 = a3.x, f3 = 1.0f + s3 + s3 * s3;
    a0.x *= f0; a0.y *= f0; a0.z *= f0; a0.w *= f0;
    a1.x *= f1; a1.y *= f1; a1.z *= f1; a1.w *= f1;
    a2.x *= f2; a2.y *= f2; a2.z *= f2; a2.w *= f2;
    a3.x *= f3; a3.y *= f3; a3.z *= f3; a3.w *= f3;
  }
  xa[nloc][col0 + 0] = a0; xa[nloc][col0 + 1] = a1;
  xa[nloc][col0 + 2] = a2; xa[nloc][col0 + 3] = a3;

  float4 p0 = {0,0,0,0}, p1 = {0,0,0,0}, p2 = {0,0,0,0}, p3 = {0,0,0,0};
  for (int hh = 0; hh < 64; ++hh) {
    float4 xv = xa[nloc][hh];
    float4 wm = *(const float4*)&sProd[hh * 64 + col0];
    p0.x = fmaf(xv.x, wm.x, p0.x); p0.y = fmaf(xv.y, wm.x, p0.y);
    p0.z = fmaf(xv.z, wm.x, p0.z); p0.w = fmaf(xv.w, wm.x, p0.w);
    p1.x = fmaf(xv.x, wm.y, p1.x); p1.y = fmaf(xv.y, wm.y, p1.y);
    p1.z = fmaf(xv.z, wm.y, p1.z); p1.w = fmaf(xv.w, wm.y, p1.w);
    p2.x = fmaf(xv.x, wm.z, p2.x); p2.y = fmaf(xv.y, wm.z, p2.y);
    p2.z = fmaf(xv.z, wm.z, p2.z); p2.w = fmaf(xv.w, wm.z, p2.w);
    p3.x = fmaf(xv.x, wm.w, p3.x); p3.y = fmaf(xv.y, wm.w, p3.y);
    p3.z = fmaf(xv.z, wm.w, p3.z); p3.w = fmaf(xv.w, wm.w, p3.w);
  }
  *(float4*)&nf0[(size_t)n * 64 + col0] = make_float4(p0.x, p1.x, p2.x, p3.x);
  {
    float4* v3p = (float4*)&v3[(size_t)n * 192 + col0 * 3];
    v3p[0] = make_float4(p0.y, p0.z, p0.w, p1.y);
    v3p[1] = make_float4(p1.z, p1.w, p2.y, p2.z);
    v3p[2] = make_float4(p2.w, p3.y, p3.z, p3.w);
  }
  if (Wup_next) {
    xa[nloc][col0 + 0] = p0; xa[nloc][col0 + 1] = p1;
    xa[nloc][col0 + 2] = p2; xa[nloc][col0 + 3] = p3;
    float u0 = 0.f, u1 = 0.f, u2 = 0.f, u3 = 0.f;
    for (int hh = 0; hh < 64; ++hh) {
      float xs = xa[nloc][hh].x;
      float4 wu = *(const float4*)&sUp[hh * 64 + col0];
      u0 = fmaf(xs, wu.x, u0); u1 = fmaf(xs, wu.y, u1);
      u2 = fmaf(xs, wu.z, u2); u3 = fmaf(xs, wu.w, u3);
    }
    *(float4*)&nfup0[(size_t)n * 64 + col0] = make_float4(u0, u1, u2, u3);
  }
}

// k_readout_mlp v2 (unchanged from round 8)
__global__ __launch_bounds__(256) void k_readout_mlp(
    const float* __restrict__ nf0, const float* __restrict__ v3,
    const float* __restrict__ Wro1, const float* __restrict__ bro1,
    const float* __restrict__ Wg, const float* __restrict__ wvv,
    const float* __restrict__ Wro2,
    const float* __restrict__ Wmlp1, const float* __restrict__ bmlp1,
    const float* __restrict__ Wmlp2, const float* __restrict__ bmlp2,
    float* __restrict__ pos, float* __restrict__ h) {
  __shared__ float sR[4096];
  __shared__ float sG[4096];
  __shared__ float sRo2[4096];
  __shared__ float sM1[8192];
  __shared__ float sM2[4096];
  __shared__ float xs[16][68];
  __shared__ float xh[16][68];
  __shared__ float xq[16][68];
  for (int i = threadIdx.x; i < 4096; i += 256) {
    sR[i] = Wro1[i]; sG[i] = Wg[i]; sRo2[i] = Wro2[i]; sM2[i] = Wmlp2[i];
  }
  for (int i = threadIdx.x; i < 8192; i += 256) sM1[i] = Wmlp1[i];
  int nb = blockIdx.x * 16;
  for (int i = threadIdx.x; i < 1024; i += 256) {
    xs[i >> 6][i & 63] = nf0[(size_t)nb * 64 + i];
    xh[i >> 6][i & 63] = h[(size_t)nb * 64 + i];
  }
  __syncthreads();

  int lane = threadIdx.x & 63, w = threadIdx.x >> 6;
  int q = lane >> 4, c16 = lane & 15;
  int nloc = w * 4 + q;
  int n = nb + nloc;
  int col0 = c16 * 4;

  float qa0 = 0, qa1 = 0, qa2 = 0, qa3 = 0;
  float ga0 = 0, ga1 = 0, ga2 = 0, ga3 = 0;
  for (int m = 0; m < 64; ++m) {
    float x = xs[nloc][m];
    float4 wr = *(const float4*)&sR[m * 64 + col0];
    float4 wg = *(const float4*)&sG[m * 64 + col0];
    qa0 = fmaf(x, wr.x, qa0); qa1 = fmaf(x, wr.y, qa1);
    qa2 = fmaf(x, wr.z, qa2); qa3 = fmaf(x, wr.w, qa3);
    ga0 = fmaf(x, wg.x, ga0); ga1 = fmaf(x, wg.y, ga1);
    ga2 = fmaf(x, wg.z, ga2); ga3 = fmaf(x, wg.w, ga3);
  }
  float4 b1v = *(const float4*)&bro1[col0];
  float q0 = silu_f(qa0 + b1v.x), q1 = silu_f(qa1 + b1v.y);
  float q2 = silu_f(qa2 + b1v.z), q3 = silu_f(qa3 + b1v.w);
  float g0 = silu_f(ga0), g1 = silu_f(ga1), g2 = silu_f(ga2), g3 = silu_f(ga3);

  {
    float4 wv4 = *(const float4*)&wvv[col0];
    const float4* v3p = (const float4*)&v3[(size_t)n * 192 + col0 * 3];
    float4 va = v3p[0], vb = v3p[1], vc = v3p[2];
    float gw0 = g0 * wv4.x, gw1 = g1 * wv4.y, gw2 = g2 * wv4.z, gw3 = g3 * wv4.w;
    float p0 = va.x * gw0 + va.w * gw1 + vb.z * gw2 + vc.y * gw3;
    float p1 = va.y * gw0 + vb.x * gw1 + vb.w * gw2 + vc.z * gw3;
    float p2 = va.z * gw0 + vb.y * gw1 + vc.x * gw2 + vc.w * gw3;
#pragma unroll
    for (int m = 1; m < 16; m <<= 1) {
      p0 += __shfl_xor(p0, m);
      p1 += __shfl_xor(p1, m);
      p2 += __shfl_xor(p2, m);
    }
    if (c16 == 0) {
      pos[n * 3 + 0] += p0;
      pos[n * 3 + 1] += p1;
      pos[n * 3 + 2] += p2;
    }
  }

  *(float4*)&xq[nloc][col0] = make_float4(q0, q1, q2, q3);
  float s20 = 0, s21 = 0, s22 = 0, s23 = 0;
  for (int m = 0; m < 64; ++m) {
    float x = xq[nloc][m];
    float4 w2 = *(const float4*)&sRo2[m * 64 + col0];
    s20 = fmaf(x, w2.x, s20); s21 = fmaf(x, w2.y, s21);
    s22 = fmaf(x, w2.z, s22); s23 = fmaf(x, w2.w, s23);
  }
  *(float4*)&xs[nloc][col0] = make_float4(s20, s21, s22, s23);

  float4 bm1 = *(const float4*)&bmlp1[col0];
  float u0 = bm1.x, u1 = bm1.y, u2 = bm1.z, u3 = bm1.w;
  for (int m = 0; m < 64; ++m) {
    float xm = xh[nloc][m];
    float4 m1 = *(const float4*)&sM1[m * 64 + col0];
    u0 = fmaf(xm, m1.x, u0); u1 = fmaf(xm, m1.y, u1);
    u2 = fmaf(xm, m1.z, u2); u3 = fmaf(xm, m1.w, u3);
  }
  for (int m = 0; m < 64; ++m) {
    float xm = xs[nloc][m];
    float4 m1 = *(const float4*)&sM1[(64 + m) * 64 + col0];
    u0 = fmaf(xm, m1.x, u0); u1 = fmaf(xm, m1.y, u1);
    u2 = fmaf(xm, m1.z, u2); u3 = fmaf(xm, m1.w, u3);
  }
  u0 = silu_f(u0); u1 = silu_f(u1); u2 = silu_f(u2); u3 = silu_f(u3);
  *(float4*)&xq[nloc][col0] = make_float4(u0, u1, u2, u3);

  float4 bm2 = *(const float4*)&bmlp2[col0];
  float4 hold = *(float4*)&xh[nloc][col0];
  float h0 = hold.x + bm2.x, h1 = hold.y + bm2.y;
  float h2 = hold.z + bm2.z, h3 = hold.w + bm2.w;
  for (int m = 0; m < 64; ++m) {
    float um = xq[nloc][m];
    float4 m2 = *(const float4*)&sM2[m * 64 + col0];
    h0 = fmaf(um, m2.x, h0); h1 = fmaf(um, m2.y, h1);
    h2 = fmaf(um, m2.z, h2); h3 = fmaf(um, m2.w, h3);
  }
  *(float4*)&h[(size_t)n * 64 + col0] = make_float4(h0, h1, h2, h3);
}

// ---------------- outputs ----------------
__global__ __launch_bounds__(256) void k_pred(
    const float* __restrict__ h, const float* __restrict__ Wout,
    const float* __restrict__ bout, float* __restrict__ out) {
  __shared__ float sW[704];
  for (int i = threadIdx.x; i < 704; i += 256) sW[i] = Wout[i];
  __syncthreads();
  int n = blockIdx.x * 256 + threadIdx.x;
  if (n >= NN) return;
  float acc[10];
#pragma unroll
  for (int j = 0; j < 10; ++j) acc[j] = bout[j];
  const float* row = h + (size_t)n * 64;
  for (int hh = 0; hh < 64; ++hh) {
    float hv = row[hh];
#pragma unroll
    for (int j = 0; j < 10; ++j) acc[j] = fmaf(hv, sW[hh * 11 + j], acc[j]);
  }
  float* orow = out + (size_t)n * 10;
#pragma unroll
  for (int j = 0; j < 10; ++j) orow[j] = acc[j];
}

__global__ __launch_bounds__(256) void k_batch(
    const int* __restrict__ batch, const float* __restrict__ pos,
    float* __restrict__ bacc) {
  int n = blockIdx.x * 256 + threadIdx.x;
  int lane = threadIdx.x & 63;
  bool valid = n < NN;
  int b = valid ? batch[n] : -1;
  float p0 = valid ? pos[n * 3 + 0] : 0.f;
  float p1 = valid ? pos[n * 3 + 1] : 0.f;
  float p2 = valid ? pos[n * 3 + 2] : 0.f;
  float c  = valid ? 1.f : 0.f;
#pragma unroll
  for (int d = 1; d < 64; d <<= 1) {
    float q0 = __shfl_down(p0, d);
    float q1 = __shfl_down(p1, d);
    float q2 = __shfl_down(p2, d);
    float qc = __shfl_down(c, d);
    int bd   = __shfl_down(b, d);
    if (lane + d < 64 && bd == b) { p0 += q0; p1 += q1; p2 += q2; c += qc; }
  }
  int bprev = __shfl_up(b, 1);
  bool head = valid && (lane == 0 || bprev != b);
  if (head) {
    atomicAdd(&bacc[b * 4 + 0], p0);
    atomicAdd(&bacc[b * 4 + 1], p1);
    atomicAdd(&bacc[b * 4 + 2], p2);
    atomicAdd(&bacc[b * 4 + 3], c);
  }
}

__global__ __launch_bounds__(256) void k_predpos(
    const int* __restrict__ batch, const float* __restrict__ pos,
    const float* __restrict__ pos0, const float* __restrict__ bacc,
    float* __restrict__ out) {
  int n = blockIdx.x * 256 + threadIdx.x;
  if (n >= NN) return;
  int b = batch[n];
  float cnt = fmaxf(bacc[b * 4 + 3], 1.0f);
#pragma unroll
  for (int c = 0; c < 3; ++c)
    out[NN * 10 + n * 3 + c] = pos[n * 3 + c] - bacc[b * 4 + c] / cnt - pos0[n * 3 + c];
}

extern "C" void kernel_launch(void* const* d_in, const int* in_sizes, int n_in,
                              void* d_out, int out_size, void* d_ws, size_t ws_size,
                              hipStream_t stream) {
  const float* positions = (const float*)d_in[0];
  const float* node_attrs = (const float*)d_in[1];
  const float* t_in = (const float*)d_in[2];
  const float* shifts = (const float*)d_in[3];
  const int* batch = (const int*)d_in[4];
  const int* edge_index = (const int*)d_in[5];
  const float* W_emb = (const float*)d_in[6];
  const float* b_emb = (const float*)d_in[7];
  const float* W_out = (const float*)d_in[8];
  const float* b_out = (const float*)d_in[9];
  const float* Wr1 = (const float*)d_in[10];
  const float* br1 = (const float*)d_in[11];
  const float* Wr2 = (const float*)d_in[12];
  const float* W_up = (const float*)d_in[13];
  const float* W_mix = (const float*)d_in[14];
  const float* W_prod = (const float*)d_in[15];
  const float* Wro1 = (const float*)d_in[16];
  const float* bro1 = (const float*)d_in[17];
  const float* Wro2 = (const float*)d_in[18];
  const float* Wg = (const float*)d_in[19];
  const float* wv = (const float*)d_in[20];
  const float* Wmlp1 = (const float*)d_in[21];
  const float* bmlp1 = (const float*)d_in[22];
  const float* Wmlp2 = (const float*)d_in[23];
  const float* bmlp2 = (const float*)d_in[24];

  float* ws = (float*)d_ws;
  float* pos_cur = ws + OFF_POS;
  float* hbuf    = ws + OFF_H;
  float* nf0     = ws + OFF_NF0;
  float* nfup0   = ws + OFF_NUP;
  float* v3      = ws + OFF_V3;
  float* table   = ws + OFF_TAB;
  float4* agg    = (float4*)(ws + OFF_AGG);
  int* edgelist  = (int*)(ws + OFF_EL);
  int* csroff    = (int*)(ws + OFF_CSR);
  int* counts    = (int*)(ws + OFF_CNT);
  int* cursor    = (int*)(ws + OFF_CUR);
  float* bacc    = ws + OFF_BACC;

  hipMemsetAsync(counts, 0, (WS_END - OFF_CNT) * sizeof(float), stream);

  k_embed_count_up<<<3125, 256, 0, stream>>>(positions, node_attrs, t_in, batch,
                                             W_emb, b_emb, W_up,
                                             hbuf, nf0, pos_cur, nfup0,
                                             edge_index, counts);
  k_scan<<<1, 1024, 0, stream>>>(counts, csroff);
  k_scatter<<<625, 256, 0, stream>>>(edge_index, csroff, cursor, edgelist);
  k_tables<<<2048, 256, 0, stream>>>(Wr1, br1, Wr2, table);

  for (int i = 0; i < 2; ++i) {
    k_msg<<<2500, 256, 0, stream>>>(edge_index, shifts, pos_cur, nfup0,
                                    csroff, edgelist,
                                    table + (size_t)i * 262144, agg);
    k_mix_prod<<<625, 256, 0, stream>>>(agg, W_mix + i * 4096, W_prod + i * 4096,
                                        nf0, v3,
                                        (i == 0) ? (W_up + 4096) : nullptr, nfup0);
    k_readout_mlp<<<625, 256, 0, stream>>>(nf0, v3, Wro1 + i * 4096, bro1 + i * 64,
                                           Wg + i * 4096, wv + i * 64,
                                           Wro2 + i * 4096,
                                           Wmlp1 + i * 8192, bmlp1 + i * 64,
                                           Wmlp2 + i * 4096, bmlp2 + i * 64,
                                           pos_cur, hbuf);
  }

  k_pred<<<40, 256, 0, stream>>>(hbuf, W_out, b_out, (float*)d_out);
  k_batch<<<40, 256, 0, stream>>>(batch, pos_cur, bacc);
  k_predpos<<<40, 256, 0, stream>>>(batch, pos_cur, positions, bacc, (float*)d_out);
}